// Round 1
// baseline (717.580 us; speedup 1.0000x reference)
//
#include <hip/hip_runtime.h>
#include <stdint.h>

#define CDIM   256
#define KCODES 1024
#define HWSZ   4096
#define NROWS  131072
// packed-key screen: flag threshold on 10-bit-truncated gap.
// original verified DELTA=4e-4; truncation of top-2 biased values < 6.2e-5
// (biased values provably in [0.25,1)), so 4.7e-4 keeps guaranteed-flag band >= 4e-4.
#define DELTA_P 4.7e-4f

// workspace layout (bytes)
#define WS_BQ    0          // 4 KB   fp32 Bq[k]
#define WS_IDX   4096       // 512 KB int   idx[n]
#define WS_CBBF  528384     // 512 KB bf16  cbbf[k][c]
#define WS_CNT   1052672    // 4 B (padded 128) flagged count
#define WS_LIST  1052800    // 512 KB int flagged row list

typedef __attribute__((ext_vector_type(8))) short short8;
typedef __attribute__((ext_vector_type(4))) float f32x4;

__device__ inline unsigned short bf16rne(float f) {
    uint32_t u = __float_as_uint(f);
    u += 0x7FFF + ((u >> 16) & 1);
    return (unsigned short)(u >> 16);
}

__device__ __forceinline__ unsigned umin32(unsigned a, unsigned b) { return a < b ? a : b; }
__device__ __forceinline__ unsigned umax32(unsigned a, unsigned b) { return a > b ? a : b; }

// ---------- Bq[k] = np.sum(cb_row^2), numpy pairwise tree (verified r2) ----------
__global__ void codesq_kernel(const float* __restrict__ cb, float* __restrict__ Bq) {
#pragma clang fp contract(off)
    int k = blockIdx.x * 256 + threadIdx.x;
    if (k >= KCODES) return;
    const float* er = cb + (size_t)k * CDIM;
    float half_s[2];
    for (int h = 0; h < 2; ++h) {
        float r[8];
        #pragma unroll
        for (int j = 0; j < 8; ++j) { float v = er[h*128 + j]; r[j] = v * v; }
        for (int i = 8; i < 128; i += 8) {
            #pragma unroll
            for (int j = 0; j < 8; ++j) { float v = er[h*128 + i + j]; float sq = v*v; r[j] = r[j] + sq; }
        }
        half_s[h] = ((r[0]+r[1]) + (r[2]+r[3])) + ((r[4]+r[5]) + (r[6]+r[7]));
    }
    Bq[k] = half_s[0] + half_s[1];
}

// ---------- cb fp32 -> bf16 (+ zero flag counter) ----------
__global__ void cbcvt_kernel(const float* __restrict__ cb, unsigned short* __restrict__ cbbf,
                             int* __restrict__ counter) {
    int i = blockIdx.x * 256 + threadIdx.x;      // 65536 float4 groups
    float4 v = ((const float4*)cb)[i];
    ushort4 o;
    o.x = bf16rne(v.x); o.y = bf16rne(v.y); o.z = bf16rne(v.z); o.w = bf16rne(v.w);
    ((ushort4*)cbbf)[i] = o;
    if (i == 0) *counter = 0;
}

// ---------- MFMA bf16 screen: per-row top2 of (|e|^2 - 2 x.e) ----------
// v2 changes vs 778.8us baseline:
//  * A fragments hoisted to registers ONCE (32x short8 = 128 VGPR) -> LDS reads /8
//  * top-2 state packed into u32 keys: bits(s+0.75) & ~0x3FF | k
//    - +0.75 bias provably keeps s' in (0.25, 1.25): |2 x.e| <= 2*248*9.77e-4 < 0.5
//    - positive-float bit order is monotone; min-u32 gives argmin w/ lowest-index tiebreak
//    - NaN s' -> large key -> ties at top -> flagged -> exact rescore (NaN-safe kept)
__global__ __launch_bounds__(256, 2)
void screen_kernel(const float* __restrict__ x, const unsigned short* __restrict__ cbbf,
                   const float* __restrict__ Bq,
                   int* __restrict__ idx_out, float* __restrict__ outF,
                   int* __restrict__ flag_list, int* __restrict__ counter) {
    __shared__ unsigned short xs[64 * 264];      // [row][c], pad 256->264 (A operand)
    __shared__ unsigned int sRed[4][64][2];

    const int t = threadIdx.x;
    const int w = t >> 6, l = t & 63;
    const int l15 = l & 15, quad = l >> 4;
    const int r0 = blockIdx.x * 64;
    const float* xbase = x + (size_t)(r0 >> 12) * (CDIM * HWSZ) + (r0 & 4095);

    // ---- stage x tile: fp32 [c][row] global -> bf16 [row][c] LDS (once, unchanged) ----
    {
        int cbase = (t >> 4) * 2;
        int row4  = (t & 15) * 4;
        for (int it = 0; it < 8; ++it) {
            int c = cbase + it * 32;
            float4 fa = *(const float4*)(xbase + (size_t)c * HWSZ + row4);
            float4 fb = *(const float4*)(xbase + (size_t)(c + 1) * HWSZ + row4);
            *(uint32_t*)&xs[(row4+0)*264 + c] = (uint32_t)bf16rne(fa.x) | ((uint32_t)bf16rne(fb.x) << 16);
            *(uint32_t*)&xs[(row4+1)*264 + c] = (uint32_t)bf16rne(fa.y) | ((uint32_t)bf16rne(fb.y) << 16);
            *(uint32_t*)&xs[(row4+2)*264 + c] = (uint32_t)bf16rne(fa.z) | ((uint32_t)bf16rne(fb.z) << 16);
            *(uint32_t*)&xs[(row4+3)*264 + c] = (uint32_t)bf16rne(fa.w) | ((uint32_t)bf16rne(fb.w) << 16);
        }
    }

    __syncthreads();

    // ---- hoist ALL A fragments into registers (read LDS once, reuse across all 8 kt) ----
    short8 af[8][4];
    #pragma unroll
    for (int step = 0; step < 8; ++step)
        #pragma unroll
        for (int rf = 0; rf < 4; ++rf)
            af[step][rf] = *(const short8*)&xs[(rf*16 + l15)*264 + step*32 + quad*8];

    // this wave's B base: codes w*32 + cf*16 + l15, k-chunk quad*8 (16B contiguous)
    const unsigned short* bbase = cbbf + (size_t)(w*32 + l15) * CDIM + quad * 8;
    const int kbase = w*32 + l15;

    unsigned int K1[16], K2[16];
    #pragma unroll
    for (int i = 0; i < 16; ++i) { K1[i] = 0xFFFFFFFFu; K2[i] = 0xFFFFFFFFu; }

    for (int kt = 0; kt < 8; ++kt) {
        // biased Bq for this kt's two code fragments (prefetch before MFMA block)
        float bqp0 = Bq[kt*128 + kbase]      + 0.75f;
        float bqp1 = Bq[kt*128 + kbase + 16] + 0.75f;

        f32x4 acc[4][2];
        #pragma unroll
        for (int rf = 0; rf < 4; ++rf)
            #pragma unroll
            for (int cf = 0; cf < 2; ++cf) acc[rf][cf] = (f32x4){0.f, 0.f, 0.f, 0.f};

        #pragma unroll
        for (int step = 0; step < 8; ++step) {    // k-chunk of 32: c = step*32 + quad*8 + j
            int koff = step * 32;
            short8 bfr0 = *(const short8*)(bbase + (size_t)(kt*128)      * CDIM + koff);
            short8 bfr1 = *(const short8*)(bbase + (size_t)(kt*128 + 16) * CDIM + koff);
            #pragma unroll
            for (int rf = 0; rf < 4; ++rf) {
                acc[rf][0] = __builtin_amdgcn_mfma_f32_16x16x32_bf16(af[step][rf], bfr0, acc[rf][0], 0, 0, 0);
                acc[rf][1] = __builtin_amdgcn_mfma_f32_16x16x32_bf16(af[step][rf], bfr1, acc[rf][1], 0, 0, 0);
            }
        }

        // epilogue: key = bits(Bq[k]+0.75 - 2*dot) & ~0x3FF | k ; running packed top2
        unsigned int kk0 = (unsigned)(kt*128 + kbase);
        unsigned int kk1 = kk0 + 16u;
        #pragma unroll
        for (int rf = 0; rf < 4; ++rf)
            #pragma unroll
            for (int reg = 0; reg < 4; ++reg) {
                int st = rf*4 + reg;
                {
                    float s = fmaf(-2.f, acc[rf][0][reg], bqp0);
                    unsigned int key = (__float_as_uint(s) & 0xFFFFFC00u) | kk0;
                    unsigned int t1 = umin32(key, K1[st]);
                    unsigned int t2 = umax32(key, K1[st]);
                    K1[st] = t1;
                    K2[st] = umin32(t2, K2[st]);
                }
                {
                    float s = fmaf(-2.f, acc[rf][1][reg], bqp1);
                    unsigned int key = (__float_as_uint(s) & 0xFFFFFC00u) | kk1;
                    unsigned int t1 = umin32(key, K1[st]);
                    unsigned int t2 = umax32(key, K1[st]);
                    K1[st] = t1;
                    K2[st] = umin32(t2, K2[st]);
                }
            }
    }

    // butterfly merge across the 16 lanes (same quad, disjoint codes, same rows)
    #pragma unroll
    for (int st = 0; st < 16; ++st) {
        #pragma unroll
        for (int m = 1; m < 16; m <<= 1) {
            unsigned int o1 = (unsigned int)__shfl_xor((int)K1[st], m, 64);
            unsigned int o2 = (unsigned int)__shfl_xor((int)K2[st], m, 64);
            // merge two sorted pairs -> top2 of union
            unsigned int n2 = umin32(umax32(K1[st], o1), umin32(K2[st], o2));
            K1[st] = umin32(K1[st], o1);
            K2[st] = n2;
        }
    }
    if (l15 == 0) {
        #pragma unroll
        for (int rf = 0; rf < 4; ++rf)
            #pragma unroll
            for (int reg = 0; reg < 4; ++reg) {
                int r = rf*16 + quad*4 + reg;
                int st = rf*4 + reg;
                sRed[w][r][0] = K1[st];
                sRed[w][r][1] = K2[st];
            }
    }
    __syncthreads();
    if (t < 64) {
        unsigned int A1 = sRed[0][t][0], A2 = sRed[0][t][1];
        #pragma unroll
        for (int ww = 1; ww < 4; ++ww) {
            unsigned int B1 = sRed[ww][t][0], B2 = sRed[ww][t][1];
            unsigned int n2 = umin32(umax32(A1, B1), umin32(A2, B2));
            A1 = umin32(A1, B1);
            A2 = n2;
        }
        int row = r0 + t;
        int k1i = (int)(A1 & 1023u);
        idx_out[row] = k1i;
        outF[row] = (float)k1i;
        float v1 = __uint_as_float(A1 & 0xFFFFFC00u);
        float v2 = __uint_as_float(A2 & 0xFFFFFC00u);
        if (!(v2 - v1 > DELTA_P)) {               // NaN-safe: garbage -> flagged -> exact path
            int pos = atomicAdd(counter, 1);
            flag_list[pos] = row;
        }
    }
}

// ---------- exact np-fp32 rescore of flagged rows (LDS-staged codebook) ----------
// Per (row,code): single fp32 fmaf chain c=0..255 ascending; T1=A+Bq; s=T1-2*acc.
// Bit-identical values to the r2 kernel verified on all 131072 rows. UNCHANGED.
__global__ __launch_bounds__(256)
void rescore_kernel(const float* __restrict__ x, const float* __restrict__ cb,
                    const float* __restrict__ Bq,
                    const int* __restrict__ flag_list, const int* __restrict__ counter,
                    int* __restrict__ idx_out, float* __restrict__ outF) {
    __shared__ float xsh[8][264];
    __shared__ float cbs[64 * 260];     // 64 codes x 256c (+4 pad)
    __shared__ float sA[8];
    __shared__ int   rows_s[8];

    int cnt = *counter;
    int nbat = (cnt + 7) >> 3;
    for (int bat = blockIdx.x; bat < nbat; bat += gridDim.x) {
        __syncthreads();
        if (threadIdx.x < 8) {
            int j = bat * 8 + threadIdx.x;
            rows_s[threadIdx.x] = (j < cnt) ? flag_list[j] : -1;
        }
        __syncthreads();
        // stage 8 x-rows (exact fp32)
        {
            int rr = threadIdx.x >> 5;
            int c0 = (threadIdx.x & 31) * 8;
            int row = rows_s[rr]; if (row < 0) row = rows_s[0];
            const float* xr = x + (size_t)(row >> 12) * (CDIM * HWSZ) + (row & 4095);
            #pragma unroll
            for (int j = 0; j < 8; ++j)
                xsh[rr][c0 + j] = xr[(size_t)(c0 + j) * HWSZ];
        }
        __syncthreads();
        // A[r] = np.sum(x^2) via the verified numpy pairwise tree
        if (threadIdx.x < 8) {
#pragma clang fp contract(off)
            const float* xr = &xsh[threadIdx.x][0];
            float hs[2];
            for (int h = 0; h < 2; ++h) {
                float rr8[8];
                #pragma unroll
                for (int j = 0; j < 8; ++j) { float v = xr[h*128 + j]; rr8[j] = v * v; }
                for (int i = 8; i < 128; i += 8) {
                    #pragma unroll
                    for (int j = 0; j < 8; ++j) { float v = xr[h*128 + i + j]; float sq = v*v; rr8[j] = rr8[j] + sq; }
                }
                hs[h] = ((rr8[0]+rr8[1]) + (rr8[2]+rr8[3])) + ((rr8[4]+rr8[5]) + (rr8[6]+rr8[7]));
            }
            sA[threadIdx.x] = hs[0] + hs[1];
        }
        __syncthreads();

        const int r     = threadIdx.x >> 5;     // row 0..7
        const int cpair = threadIdx.x & 31;     // code slot within tile
        const float Ar  = sA[r];
        float bv = 3.4e38f; int bk = 0;

        for (int tile = 0; tile < 16; ++tile) {
            __syncthreads();
            // stage 64 codes coalesced: thread -> (code kc, 64-float segment seg)
            {
                int kc = threadIdx.x >> 2, seg = threadIdx.x & 3;
                const float* crow = cb + (size_t)(tile*64 + kc) * CDIM + seg * 64;
                float* dst = &cbs[kc * 260 + seg * 64];
                #pragma unroll
                for (int i = 0; i < 16; ++i)
                    *(float4*)&dst[i*4] = *(const float4*)&crow[i*4];
            }
            __syncthreads();
            // two exact chains per thread; kl = cpair + j*32 (bank-spread + k-ascending)
            #pragma unroll
            for (int j = 0; j < 2; ++j) {
                int kl = cpair + j * 32;
                const float* e  = &cbs[kl * 260];
                const float* xr = &xsh[r][0];
                float acc = 0.f;
                for (int c4 = 0; c4 < 64; ++c4) {
                    float4 ev = *(const float4*)&e[c4*4];
                    float4 xv = *(const float4*)&xr[c4*4];
                    acc = fmaf(xv.x, ev.x, acc);
                    acc = fmaf(xv.y, ev.y, acc);
                    acc = fmaf(xv.z, ev.z, acc);
                    acc = fmaf(xv.w, ev.w, acc);
                }
                int k = tile*64 + kl;
                float T1 = Ar + Bq[k];
                float s  = T1 - 2.0f * acc;
                if (s < bv) { bv = s; bk = k; }      // k ascending within thread
            }
        }
        // reduce across the 32 threads of each row (lanes [0..31] / [32..63] per wave)
        #pragma unroll
        for (int m = 1; m < 32; m <<= 1) {
            float ov = __shfl_xor(bv, m, 64);
            int   ok = __shfl_xor(bk, m, 64);
            if (ov < bv || (ov == bv && ok < bk)) { bv = ov; bk = ok; }
        }
        if ((threadIdx.x & 31) == 0) {
            int row = rows_s[r];
            if (row >= 0) { idx_out[row] = bk; outF[row] = (float)bk; }
        }
    }
}

// ---------- gather codebook rows + NHWC->NCHW transpose (verified r2, unchanged) ----------
__global__ __launch_bounds__(256)
void gather_kernel(const float* __restrict__ cb, const int* __restrict__ idx,
                   float* __restrict__ out) {
    __shared__ int   sIdx[64];
    __shared__ float tile[64 * 129];
    const int t  = threadIdx.x;
    const int bh = blockIdx.x;
    const int b  = bh >> 6, h = bh & 63;

    if (t < 64) {
        int id = idx[bh * 64 + t];
        sIdx[t] = id;
        out[bh * 64 + t] = (float)id;
    }
    __syncthreads();

    float* qout = out + NROWS + (size_t)b * (CDIM * HWSZ) + h * 64;

    for (int c0 = 0; c0 < CDIM; c0 += 128) {
        if (c0) __syncthreads();
        {
            int ww = t >> 2, seg = t & 3;
            const float* crow = cb + (size_t)sIdx[ww] * CDIM + c0;
            #pragma unroll
            for (int jj = 0; jj < 8; ++jj) {
                int f = seg + 4 * jj;
                float4 v = *(const float4*)(crow + 4 * f);
                float* dst = &tile[ww * 129 + 4 * f];
                dst[0] = v.x; dst[1] = v.y; dst[2] = v.z; dst[3] = v.w;
            }
        }
        __syncthreads();
        {
            int g = t >> 4, w4 = (t & 15) * 4;
            #pragma unroll
            for (int it = 0; it < 8; ++it) {
                int cl = it * 16 + g;
                float4 v;
                v.x = tile[(w4 + 0) * 129 + cl];
                v.y = tile[(w4 + 1) * 129 + cl];
                v.z = tile[(w4 + 2) * 129 + cl];
                v.w = tile[(w4 + 3) * 129 + cl];
                *(float4*)(qout + (size_t)(c0 + cl) * HWSZ + w4) = v;
            }
        }
    }
}

extern "C" void kernel_launch(void* const* d_in, const int* in_sizes, int n_in,
                              void* d_out, int out_size, void* d_ws, size_t ws_size,
                              hipStream_t stream) {
    const float* x  = (const float*)d_in[0];
    const float* cb = (const float*)d_in[1];
    char* ws = (char*)d_ws;
    float*          Bq    = (float*)(ws + WS_BQ);
    int*            idxbf = (int*)(ws + WS_IDX);
    unsigned short* cbbf  = (unsigned short*)(ws + WS_CBBF);
    int*            cnt   = (int*)(ws + WS_CNT);
    int*            list  = (int*)(ws + WS_LIST);
    float*          out   = (float*)d_out;

    codesq_kernel<<<KCODES / 256, 256, 0, stream>>>(cb, Bq);
    cbcvt_kernel <<<256, 256, 0, stream>>>(cb, cbbf, cnt);
    screen_kernel<<<NROWS / 64, 256, 0, stream>>>(x, cbbf, Bq, idxbf, out, list, cnt);
    rescore_kernel<<<2048, 256, 0, stream>>>(x, cb, Bq, list, cnt, idxbf, out);
    gather_kernel<<<32 * 64, 256, 0, stream>>>(cb, idxbf, out);
}

// Round 2
// 559.230 us; speedup vs baseline: 1.2832x; 1.2832x over previous
//
#include <hip/hip_runtime.h>
#include <stdint.h>

#define CDIM   256
#define KCODES 1024
#define HWSZ   4096
#define NROWS  131072
// packed-key screen: flag threshold on 10-bit-truncated gap.
// original verified DELTA=4e-4; truncation of top-2 biased values < 1.22e-4
// (biased values provably in (0.25,1.25)), so 4.7e-4 keeps guaranteed-flag band >= 4e-4.
#define DELTA_P 4.7e-4f

// workspace layout (bytes)
#define WS_BQ    0          // 4 KB   fp32 Bq[k]
#define WS_IDX   4096       // 512 KB int   idx[n]
#define WS_CBBF  528384     // 512 KB bf16  cbbf[k][c]
#define WS_CNT   1052672    // 4 B (padded 128) flagged count
#define WS_LIST  1052800    // 512 KB int flagged row list

typedef __attribute__((ext_vector_type(8))) short short8;
typedef __attribute__((ext_vector_type(4))) float f32x4;

__device__ inline unsigned short bf16rne(float f) {
    uint32_t u = __float_as_uint(f);
    u += 0x7FFF + ((u >> 16) & 1);
    return (unsigned short)(u >> 16);
}

__device__ __forceinline__ unsigned umin32(unsigned a, unsigned b) { return a < b ? a : b; }
__device__ __forceinline__ unsigned umax32(unsigned a, unsigned b) { return a > b ? a : b; }

// ---------- Bq[k] = np.sum(cb_row^2), numpy pairwise tree (verified r2) ----------
__global__ void codesq_kernel(const float* __restrict__ cb, float* __restrict__ Bq) {
#pragma clang fp contract(off)
    int k = blockIdx.x * 256 + threadIdx.x;
    if (k >= KCODES) return;
    const float* er = cb + (size_t)k * CDIM;
    float half_s[2];
    for (int h = 0; h < 2; ++h) {
        float r[8];
        #pragma unroll
        for (int j = 0; j < 8; ++j) { float v = er[h*128 + j]; r[j] = v * v; }
        for (int i = 8; i < 128; i += 8) {
            #pragma unroll
            for (int j = 0; j < 8; ++j) { float v = er[h*128 + i + j]; float sq = v*v; r[j] = r[j] + sq; }
        }
        half_s[h] = ((r[0]+r[1]) + (r[2]+r[3])) + ((r[4]+r[5]) + (r[6]+r[7]));
    }
    Bq[k] = half_s[0] + half_s[1];
}

// ---------- cb fp32 -> bf16 (+ zero flag counter) ----------
__global__ void cbcvt_kernel(const float* __restrict__ cb, unsigned short* __restrict__ cbbf,
                             int* __restrict__ counter) {
    int i = blockIdx.x * 256 + threadIdx.x;      // 65536 float4 groups
    float4 v = ((const float4*)cb)[i];
    ushort4 o;
    o.x = bf16rne(v.x); o.y = bf16rne(v.y); o.z = bf16rne(v.z); o.w = bf16rne(v.w);
    ((ushort4*)cbbf)[i] = o;
    if (i == 0) *counter = 0;
}

// ---------- MFMA bf16 screen: per-row top2 of (|e|^2 - 2 x.e)  (UNCHANGED from r1) ----------
__global__ __launch_bounds__(256, 2)
void screen_kernel(const float* __restrict__ x, const unsigned short* __restrict__ cbbf,
                   const float* __restrict__ Bq,
                   int* __restrict__ idx_out, float* __restrict__ outF,
                   int* __restrict__ flag_list, int* __restrict__ counter) {
    __shared__ unsigned short xs[64 * 264];      // [row][c], pad 256->264 (A operand)
    __shared__ unsigned int sRed[4][64][2];

    const int t = threadIdx.x;
    const int w = t >> 6, l = t & 63;
    const int l15 = l & 15, quad = l >> 4;
    const int r0 = blockIdx.x * 64;
    const float* xbase = x + (size_t)(r0 >> 12) * (CDIM * HWSZ) + (r0 & 4095);

    // ---- stage x tile: fp32 [c][row] global -> bf16 [row][c] LDS (once) ----
    {
        int cbase = (t >> 4) * 2;
        int row4  = (t & 15) * 4;
        for (int it = 0; it < 8; ++it) {
            int c = cbase + it * 32;
            float4 fa = *(const float4*)(xbase + (size_t)c * HWSZ + row4);
            float4 fb = *(const float4*)(xbase + (size_t)(c + 1) * HWSZ + row4);
            *(uint32_t*)&xs[(row4+0)*264 + c] = (uint32_t)bf16rne(fa.x) | ((uint32_t)bf16rne(fb.x) << 16);
            *(uint32_t*)&xs[(row4+1)*264 + c] = (uint32_t)bf16rne(fa.y) | ((uint32_t)bf16rne(fb.y) << 16);
            *(uint32_t*)&xs[(row4+2)*264 + c] = (uint32_t)bf16rne(fa.z) | ((uint32_t)bf16rne(fb.z) << 16);
            *(uint32_t*)&xs[(row4+3)*264 + c] = (uint32_t)bf16rne(fa.w) | ((uint32_t)bf16rne(fb.w) << 16);
        }
    }

    __syncthreads();

    // ---- hoist ALL A fragments into registers (read LDS once, reuse across all 8 kt) ----
    short8 af[8][4];
    #pragma unroll
    for (int step = 0; step < 8; ++step)
        #pragma unroll
        for (int rf = 0; rf < 4; ++rf)
            af[step][rf] = *(const short8*)&xs[(rf*16 + l15)*264 + step*32 + quad*8];

    // this wave's B base: codes w*32 + cf*16 + l15, k-chunk quad*8 (16B contiguous)
    const unsigned short* bbase = cbbf + (size_t)(w*32 + l15) * CDIM + quad * 8;
    const int kbase = w*32 + l15;

    unsigned int K1[16], K2[16];
    #pragma unroll
    for (int i = 0; i < 16; ++i) { K1[i] = 0xFFFFFFFFu; K2[i] = 0xFFFFFFFFu; }

    for (int kt = 0; kt < 8; ++kt) {
        float bqp0 = Bq[kt*128 + kbase]      + 0.75f;
        float bqp1 = Bq[kt*128 + kbase + 16] + 0.75f;

        f32x4 acc[4][2];
        #pragma unroll
        for (int rf = 0; rf < 4; ++rf)
            #pragma unroll
            for (int cf = 0; cf < 2; ++cf) acc[rf][cf] = (f32x4){0.f, 0.f, 0.f, 0.f};

        #pragma unroll
        for (int step = 0; step < 8; ++step) {    // k-chunk of 32: c = step*32 + quad*8 + j
            int koff = step * 32;
            short8 bfr0 = *(const short8*)(bbase + (size_t)(kt*128)      * CDIM + koff);
            short8 bfr1 = *(const short8*)(bbase + (size_t)(kt*128 + 16) * CDIM + koff);
            #pragma unroll
            for (int rf = 0; rf < 4; ++rf) {
                acc[rf][0] = __builtin_amdgcn_mfma_f32_16x16x32_bf16(af[step][rf], bfr0, acc[rf][0], 0, 0, 0);
                acc[rf][1] = __builtin_amdgcn_mfma_f32_16x16x32_bf16(af[step][rf], bfr1, acc[rf][1], 0, 0, 0);
            }
        }

        unsigned int kk0 = (unsigned)(kt*128 + kbase);
        unsigned int kk1 = kk0 + 16u;
        #pragma unroll
        for (int rf = 0; rf < 4; ++rf)
            #pragma unroll
            for (int reg = 0; reg < 4; ++reg) {
                int st = rf*4 + reg;
                {
                    float s = fmaf(-2.f, acc[rf][0][reg], bqp0);
                    unsigned int key = (__float_as_uint(s) & 0xFFFFFC00u) | kk0;
                    unsigned int t1 = umin32(key, K1[st]);
                    unsigned int t2 = umax32(key, K1[st]);
                    K1[st] = t1;
                    K2[st] = umin32(t2, K2[st]);
                }
                {
                    float s = fmaf(-2.f, acc[rf][1][reg], bqp1);
                    unsigned int key = (__float_as_uint(s) & 0xFFFFFC00u) | kk1;
                    unsigned int t1 = umin32(key, K1[st]);
                    unsigned int t2 = umax32(key, K1[st]);
                    K1[st] = t1;
                    K2[st] = umin32(t2, K2[st]);
                }
            }
    }

    #pragma unroll
    for (int st = 0; st < 16; ++st) {
        #pragma unroll
        for (int m = 1; m < 16; m <<= 1) {
            unsigned int o1 = (unsigned int)__shfl_xor((int)K1[st], m, 64);
            unsigned int o2 = (unsigned int)__shfl_xor((int)K2[st], m, 64);
            unsigned int n2 = umin32(umax32(K1[st], o1), umin32(K2[st], o2));
            K1[st] = umin32(K1[st], o1);
            K2[st] = n2;
        }
    }
    if (l15 == 0) {
        #pragma unroll
        for (int rf = 0; rf < 4; ++rf)
            #pragma unroll
            for (int reg = 0; reg < 4; ++reg) {
                int r = rf*16 + quad*4 + reg;
                int st = rf*4 + reg;
                sRed[w][r][0] = K1[st];
                sRed[w][r][1] = K2[st];
            }
    }
    __syncthreads();
    if (t < 64) {
        unsigned int A1 = sRed[0][t][0], A2 = sRed[0][t][1];
        #pragma unroll
        for (int ww = 1; ww < 4; ++ww) {
            unsigned int B1 = sRed[ww][t][0], B2 = sRed[ww][t][1];
            unsigned int n2 = umin32(umax32(A1, B1), umin32(A2, B2));
            A1 = umin32(A1, B1);
            A2 = n2;
        }
        int row = r0 + t;
        int k1i = (int)(A1 & 1023u);
        idx_out[row] = k1i;
        outF[row] = (float)k1i;
        float v1 = __uint_as_float(A1 & 0xFFFFFC00u);
        float v2 = __uint_as_float(A2 & 0xFFFFFC00u);
        if (!(v2 - v1 > DELTA_P)) {               // NaN-safe: garbage -> flagged -> exact path
            int pos = atomicAdd(counter, 1);
            flag_list[pos] = row;
        }
    }
}

// ---------- exact np-fp32 rescore of flagged rows, v2: 64-row batches, 4x4 register tile ----------
// Per (row,code): single fp32 fmaf chain c=0..255 ascending; T1=A+Bq; s=T1-2*acc.
// Chain arithmetic BIT-IDENTICAL to the verified r2 rescore; only data movement changed:
//  * 64 flagged rows per batch; each thread owns 4 rows x 4 codes -> each LDS float4
//    feeds 4 chains (0.5 loads/chain vs 2.0) -> ~4x less LDS traffic (the measured bound).
//  * cbs stored with XOR chunk-swizzle (storage permutation only; read through same map)
//    so the 4 ev reads stay bank-even at stride 256.
__global__ __launch_bounds__(256)
void rescore_kernel(const float* __restrict__ x, const float* __restrict__ cb,
                    const float* __restrict__ Bq,
                    const int* __restrict__ flag_list, const int* __restrict__ counter,
                    int* __restrict__ idx_out, float* __restrict__ outF) {
    __shared__ float xsh[64 * 256];     // 64 x-rows, exact fp32
    __shared__ float cbs[64 * 256];     // 64 codes, chunk-swizzled
    __shared__ float sA[64];
    __shared__ int   rows_s[64];

    int cnt = *counter;
    int nbat = (cnt + 63) >> 6;
    for (int bat = blockIdx.x; bat < nbat; bat += gridDim.x) {
        __syncthreads();
        if (threadIdx.x < 64) {
            int j = bat * 64 + threadIdx.x;
            rows_s[threadIdx.x] = (j < cnt) ? flag_list[j] : -1;
        }
        __syncthreads();
        // stage 64 x-rows: thread -> (row rr = t>>2, 64-float segment seg = t&3)
        {
            int rr = threadIdx.x >> 2;
            int c0 = (threadIdx.x & 3) * 64;
            int row = rows_s[rr]; if (row < 0) row = rows_s[0];
            const float* xr = x + (size_t)(row >> 12) * (CDIM * HWSZ) + (row & 4095);
            #pragma unroll 8
            for (int j = 0; j < 64; ++j)
                xsh[rr*256 + c0 + j] = xr[(size_t)(c0 + j) * HWSZ];
        }
        __syncthreads();
        // A[r] = np.sum(x^2) via the verified numpy pairwise tree (one thread per row)
        if (threadIdx.x < 64) {
#pragma clang fp contract(off)
            const float* xr = &xsh[threadIdx.x * 256];
            float hs[2];
            for (int h = 0; h < 2; ++h) {
                float rr8[8];
                #pragma unroll
                for (int j = 0; j < 8; ++j) { float v = xr[h*128 + j]; rr8[j] = v * v; }
                for (int i = 8; i < 128; i += 8) {
                    #pragma unroll
                    for (int j = 0; j < 8; ++j) { float v = xr[h*128 + i + j]; float sq = v*v; rr8[j] = rr8[j] + sq; }
                }
                hs[h] = ((rr8[0]+rr8[1]) + (rr8[2]+rr8[3])) + ((rr8[4]+rr8[5]) + (rr8[6]+rr8[7]));
            }
            sA[threadIdx.x] = hs[0] + hs[1];
        }
        __syncthreads();

        const int rq = threadIdx.x >> 4;      // row quad: rows rq*4 + 0..3
        const int cq = threadIdx.x & 15;      // code lane: codes cq + 16*j, j=0..3
        const int sw = cq & 7;                // swizzle key ((cq+16j)&7 == cq&7 for all j)
        float Ar[4];
        #pragma unroll
        for (int i = 0; i < 4; ++i) Ar[i] = sA[rq*4 + i];

        float bv[4]; int bk[4];
        #pragma unroll
        for (int i = 0; i < 4; ++i) { bv[i] = 3.4e38f; bk[i] = 0; }

        for (int tile = 0; tile < 16; ++tile) {
            __syncthreads();
            // stage 64 codes coalesced, chunk-swizzled: logical chunk lc -> storage lc^(kc&7)
            {
                int kc = threadIdx.x >> 2, seg = threadIdx.x & 3;
                const float* crow = cb + (size_t)(tile*64 + kc) * CDIM + seg * 64;
                float* dst = &cbs[kc * 256];
                int kw = kc & 7;
                #pragma unroll
                for (int i = 0; i < 16; ++i) {
                    int lc = seg*16 + i;
                    *(float4*)&dst[(lc ^ kw) * 4] = *(const float4*)&crow[i*4];
                }
            }
            __syncthreads();
            // prefetch Bq for this thread's 4 codes (hides the L2 latency under the chains)
            float bq[4];
            #pragma unroll
            for (int j = 0; j < 4; ++j) bq[j] = Bq[tile*64 + cq + j*16];

            const float* eb[4];
            #pragma unroll
            for (int j = 0; j < 4; ++j) eb[j] = &cbs[(cq + j*16) * 256];
            const float* xb[4];
            #pragma unroll
            for (int i = 0; i < 4; ++i) xb[i] = &xsh[(rq*4 + i) * 256];

            float acc[4][4];
            #pragma unroll
            for (int i = 0; i < 4; ++i)
                #pragma unroll
                for (int j = 0; j < 4; ++j) acc[i][j] = 0.f;

            #pragma unroll 2
            for (int c4 = 0; c4 < 64; ++c4) {
                int so = (c4 ^ sw) * 4;          // swizzled storage chunk for ev
                float4 ev[4], xv[4];
                #pragma unroll
                for (int j = 0; j < 4; ++j) ev[j] = *(const float4*)&eb[j][so];
                #pragma unroll
                for (int i = 0; i < 4; ++i) xv[i] = *(const float4*)&xb[i][c4*4];
                // 16 chains; within each chain the order x,y,z,w at ascending c4 is
                // EXACTLY the verified serial fmaf chain
                #pragma unroll
                for (int i = 0; i < 4; ++i)
                    #pragma unroll
                    for (int j = 0; j < 4; ++j) {
                        float a = acc[i][j];
                        a = fmaf(xv[i].x, ev[j].x, a);
                        a = fmaf(xv[i].y, ev[j].y, a);
                        a = fmaf(xv[i].z, ev[j].z, a);
                        a = fmaf(xv[i].w, ev[j].w, a);
                        acc[i][j] = a;
                    }
            }
            // finish: T1 = A + Bq; s = T1 - 2*acc  (identical ops; k ascending in j)
            #pragma unroll
            for (int j = 0; j < 4; ++j) {
                int k = tile*64 + cq + j*16;
                #pragma unroll
                for (int i = 0; i < 4; ++i) {
                    float T1 = Ar[i] + bq[j];
                    float s  = T1 - 2.0f * acc[i][j];
                    if (s < bv[i]) { bv[i] = s; bk[i] = k; }
                }
            }
        }
        // reduce across the 16 code-lanes of each row group (XOR on lane bits 0..3
        // stays within the group; rq = t>>4 is preserved)
        #pragma unroll
        for (int i = 0; i < 4; ++i) {
            float b = bv[i]; int k = bk[i];
            #pragma unroll
            for (int m = 1; m < 16; m <<= 1) {
                float ov = __shfl_xor(b, m, 64);
                int   ok = __shfl_xor(k, m, 64);
                if (ov < b || (ov == b && ok < k)) { b = ov; k = ok; }
            }
            bv[i] = b; bk[i] = k;
        }
        if (cq == 0) {
            #pragma unroll
            for (int i = 0; i < 4; ++i) {
                int row = rows_s[rq*4 + i];
                if (row >= 0) { idx_out[row] = bk[i]; outF[row] = (float)bk[i]; }
            }
        }
    }
}

// ---------- gather codebook rows + NHWC->NCHW transpose (verified r2, unchanged) ----------
__global__ __launch_bounds__(256)
void gather_kernel(const float* __restrict__ cb, const int* __restrict__ idx,
                   float* __restrict__ out) {
    __shared__ int   sIdx[64];
    __shared__ float tile[64 * 129];
    const int t  = threadIdx.x;
    const int bh = blockIdx.x;
    const int b  = bh >> 6, h = bh & 63;

    if (t < 64) {
        int id = idx[bh * 64 + t];
        sIdx[t] = id;
        out[bh * 64 + t] = (float)id;
    }
    __syncthreads();

    float* qout = out + NROWS + (size_t)b * (CDIM * HWSZ) + h * 64;

    for (int c0 = 0; c0 < CDIM; c0 += 128) {
        if (c0) __syncthreads();
        {
            int ww = t >> 2, seg = t & 3;
            const float* crow = cb + (size_t)sIdx[ww] * CDIM + c0;
            #pragma unroll
            for (int jj = 0; jj < 8; ++jj) {
                int f = seg + 4 * jj;
                float4 v = *(const float4*)(crow + 4 * f);
                float* dst = &tile[ww * 129 + 4 * f];
                dst[0] = v.x; dst[1] = v.y; dst[2] = v.z; dst[3] = v.w;
            }
        }
        __syncthreads();
        {
            int g = t >> 4, w4 = (t & 15) * 4;
            #pragma unroll
            for (int it = 0; it < 8; ++it) {
                int cl = it * 16 + g;
                float4 v;
                v.x = tile[(w4 + 0) * 129 + cl];
                v.y = tile[(w4 + 1) * 129 + cl];
                v.z = tile[(w4 + 2) * 129 + cl];
                v.w = tile[(w4 + 3) * 129 + cl];
                *(float4*)(qout + (size_t)(c0 + cl) * HWSZ + w4) = v;
            }
        }
    }
}

extern "C" void kernel_launch(void* const* d_in, const int* in_sizes, int n_in,
                              void* d_out, int out_size, void* d_ws, size_t ws_size,
                              hipStream_t stream) {
    const float* x  = (const float*)d_in[0];
    const float* cb = (const float*)d_in[1];
    char* ws = (char*)d_ws;
    float*          Bq    = (float*)(ws + WS_BQ);
    int*            idxbf = (int*)(ws + WS_IDX);
    unsigned short* cbbf  = (unsigned short*)(ws + WS_CBBF);
    int*            cnt   = (int*)(ws + WS_CNT);
    int*            list  = (int*)(ws + WS_LIST);
    float*          out   = (float*)d_out;

    codesq_kernel<<<KCODES / 256, 256, 0, stream>>>(cb, Bq);
    cbcvt_kernel <<<256, 256, 0, stream>>>(cb, cbbf, cnt);
    screen_kernel<<<NROWS / 64, 256, 0, stream>>>(x, cbbf, Bq, idxbf, out, list, cnt);
    rescore_kernel<<<2048, 256, 0, stream>>>(x, cb, Bq, list, cnt, idxbf, out);
    gather_kernel<<<32 * 64, 256, 0, stream>>>(cb, idxbf, out);
}